// Round 3
// baseline (1550.299 us; speedup 1.0000x reference)
//
#include <hip/hip_runtime.h>
#include <hip/hip_bf16.h>
#include <math.h>

#define N_NODES 50000
#define N_EDGES 800000
#define NLAYERS 8
#define ALPHA_C 0.1f
#define BN_EPS  1e-5f

typedef unsigned short u16;
typedef __attribute__((ext_vector_type(8))) short short8;
typedef __attribute__((ext_vector_type(4))) float f32x4;

static __device__ __forceinline__ u16 f2bf(float f) {
    unsigned u = __float_as_uint(f);
    unsigned r = (u + 0x7fffu + ((u >> 16) & 1u)) >> 16;
    return (u16)r;
}
static __device__ __forceinline__ float bf2f(u16 b) {
    return __uint_as_float((unsigned)b << 16);
}

// ---------------------------------------------------------------------------
// CSR build
// ---------------------------------------------------------------------------
__global__ __launch_bounds__(256) void k_init(int* cnt, int* fill, float* stats) {
    int i = blockIdx.x * 256 + threadIdx.x;
    if (i < N_NODES) { cnt[i] = 0; fill[i] = 0; }
    if (i < NLAYERS * 256) stats[i] = 0.0f;
}

__global__ __launch_bounds__(256) void k_count(const int* __restrict__ dst, int* cnt) {
    int e = blockIdx.x * 256 + threadIdx.x;
    if (e < N_EDGES) atomicAdd(&cnt[dst[e]], 1);
}

__global__ __launch_bounds__(256) void k_dinv(const int* __restrict__ cnt, float* __restrict__ dinv) {
    int i = blockIdx.x * 256 + threadIdx.x;
    if (i < N_NODES) dinv[i] = rsqrtf((float)(cnt[i] + 1));  // +1 self-loop
}

// multi-block scan: local (49 blocks x 1024) -> top (49 sums) -> add
__global__ __launch_bounds__(1024) void k_scan_local(const int* __restrict__ cnt,
                                                     int* __restrict__ rowptr, int* __restrict__ bsum) {
    __shared__ int tmp[1024];
    int t = threadIdx.x;
    int i = blockIdx.x * 1024 + t;
    int v = (i < N_NODES) ? cnt[i] : 0;
    tmp[t] = v;
    __syncthreads();
    for (int off = 1; off < 1024; off <<= 1) {
        int y = (t >= off) ? tmp[t - off] : 0;
        __syncthreads();
        tmp[t] += y;
        __syncthreads();
    }
    if (i < N_NODES) rowptr[i] = tmp[t] - v;  // local exclusive
    if (t == 1023) bsum[blockIdx.x] = tmp[t];
}

__global__ void k_scan_top(int* bsum) {  // 1 block, 64 threads, 49 entries
    __shared__ int tmp[64];
    int t = threadIdx.x;
    int v = (t < 49) ? bsum[t] : 0;
    tmp[t] = v;
    __syncthreads();
    for (int off = 1; off < 64; off <<= 1) {
        int y = (t >= off) ? tmp[t - off] : 0;
        __syncthreads();
        tmp[t] += y;
        __syncthreads();
    }
    if (t < 49) bsum[t] = tmp[t] - v;  // exclusive
}

__global__ __launch_bounds__(256) void k_scan_add(int* __restrict__ rowptr, const int* __restrict__ bsum) {
    int i = blockIdx.x * 256 + threadIdx.x;
    if (i < N_NODES) rowptr[i] += bsum[i >> 10];
    if (i == 0) rowptr[N_NODES] = N_EDGES;
}

__global__ __launch_bounds__(256) void k_scatter(const int* __restrict__ src, const int* __restrict__ dst,
                                                 const int* __restrict__ rowptr, int* fill,
                                                 int* __restrict__ ssrc) {
    int e = blockIdx.x * 256 + threadIdx.x;
    if (e < N_EDGES) {
        int d = dst[e];
        int pos = rowptr[d] + atomicAdd(&fill[d], 1);
        ssrc[pos] = src[e];
    }
}

// ---------------------------------------------------------------------------
// Weight convert: fp32 -> bf16, [j][k], XOR-swizzled (k' = k ^ ((j&7)<<3))
// wtb layout (elements): conv layer i at i*16384, lin0 at 131072, lin1 at 147456
// ---------------------------------------------------------------------------
__global__ __launch_bounds__(256) void k_convw(const float* __restrict__ conv_w,
                                               const float* __restrict__ lin0_w,
                                               const float* __restrict__ lin1_w,
                                               u16* __restrict__ wtb) {
    int t = blockIdx.x * 256 + threadIdx.x;
    if (t < 131072) {                       // conv: B[j][k] = conv_w[i][k][j]
        int j = (t >> 7) & 127, k = t & 127;
        int i = t >> 14;
        float v = conv_w[(i << 14) + (k << 7) + j];
        wtb[(t & ~127) | (k ^ ((j & 7) << 3))] = f2bf(v);
    } else if (t < 131072 + 16384) {        // lin0_w [128][128] already [j][k]
        int u = t - 131072;
        int j = u >> 7, k = u & 127;
        wtb[131072 + ((u & ~127) | (k ^ ((j & 7) << 3)))] = f2bf(lin0_w[u]);
    } else if (t < 131072 + 16384 + 8192) { // lin1_w [64][128]
        int u = t - 147456;
        int j = u >> 7, k = u & 127;
        wtb[147456 + ((u & ~127) | (k ^ ((j & 7) << 3)))] = f2bf(lin1_w[u]);
    }
}

// x (fp32 row-major) -> bf16 slice-major: xb[((j>>4)*N + row)*16 + (j&15)]
__global__ __launch_bounds__(256) void k_convx(const float* __restrict__ x, u16* __restrict__ xb) {
    size_t i = ((size_t)blockIdx.x * 256 + threadIdx.x) * 4;
    int row = (int)(i >> 7), j = (int)(i & 127);
    float4 v = *(const float4*)(x + i);
    uint2 o;
    o.x = (unsigned)f2bf(v.x) | ((unsigned)f2bf(v.y) << 16);
    o.y = (unsigned)f2bf(v.z) | ((unsigned)f2bf(v.w) << 16);
    *(uint2*)(xb + ((size_t)(j >> 4) * N_NODES + row) * 16 + (j & 15)) = o;
}

// ---------------------------------------------------------------------------
// MFMA GEMM: C[M x NT*16] = A[M x 128](bf16, SLICE-MAJOR) @ W'(bf16 [j][k] swz)
// A slice-major: element (row,k) at A[((k>>4)*N + row)*16 + (k&15)]
// mfma_f32_16x16x32_bf16: A lane l: row=l&15, k=8*(l>>4)+e ; D: col=l&15, row=4*(l>>4)+reg
// MODE 0: v=relu(acc+bias); Cout(h0,f32,row-major)=v; Cbf(hbp,slice-major)=bf16(dinv*v)
// MODE 1: v=(1-beta)*Zin + beta*acc; Cout(Z,row-major)=v; BN stats atomics (layer slice)
// MODE 2: Cout(row-major, stride NT*16) = acc/dinv[row] + bias
// ---------------------------------------------------------------------------
template<int NT, int MODE>
__global__ __launch_bounds__(256) void k_gemm_mfma(const u16* __restrict__ A,
                                                   const u16* __restrict__ Wg,
                                                   const float* __restrict__ bias,
                                                   const float* __restrict__ Zin,
                                                   float* __restrict__ Cout,
                                                   u16* __restrict__ Cbf,
                                                   float* __restrict__ stats,
                                                   const float* __restrict__ dinv,
                                                   float beta_c, int M) {
    __shared__ u16 Ws[NT * 16 * 128];
    __shared__ float sstat[256];
    int tid = threadIdx.x;

    {
        const float4* srcv = (const float4*)Wg;
        float4* dstv = (float4*)Ws;
#pragma unroll
        for (int i = 0; i < NT; ++i) dstv[tid + i * 256] = srcv[tid + i * 256];
    }
    if (MODE == 1) sstat[tid] = 0.f;

    int wave = tid >> 6, lane = tid & 63;
    int r0 = blockIdx.x * 64 + wave * 16;
    int kg = lane >> 4;            // k-group 0..3
    int cl = lane & 15;

    int arow = r0 + cl;
    int acl = arow < M ? arow : M - 1;
    short8 afrag[4];
#pragma unroll
    for (int kk = 0; kk < 4; ++kk) {
        int s = kk * 2 + (kg >> 1);  // slice of k-range kk*32+kg*8..+7
        afrag[kk] = *(const short8*)(A + ((size_t)s * N_NODES + acl) * 16 + (kg & 1) * 8);
    }

    __syncthreads();

    f32x4 acc[NT];
#pragma unroll
    for (int nt = 0; nt < NT; ++nt) {
        acc[nt] = (f32x4){0.f, 0.f, 0.f, 0.f};
        int j = nt * 16 + cl;
        const u16* wrow = Ws + j * 128;
        int sw = (j & 7) << 3;
#pragma unroll
        for (int kk = 0; kk < 4; ++kk) {
            short8 b = *(const short8*)(wrow + ((kk * 32 + kg * 8) ^ sw));
            acc[nt] = __builtin_amdgcn_mfma_f32_16x16x32_bf16(afrag[kk], b, acc[nt], 0, 0, 0);
        }
    }

    int rbase = r0 + kg * 4;
#pragma unroll
    for (int nt = 0; nt < NT; ++nt) {
        int j = nt * 16 + cl;
        float s = 0.f, ss = 0.f;
#pragma unroll
        for (int reg = 0; reg < 4; ++reg) {
            int row = rbase + reg;
            if (row >= M) continue;
            float v = acc[nt][reg];
            if (MODE == 0) {
                v = fmaxf(v + bias[j], 0.f);
                Cout[(size_t)row * 128 + j] = v;
                Cbf[((size_t)nt * N_NODES + row) * 16 + cl] = f2bf(v * dinv[row]);
            } else if (MODE == 1) {
                float zin = Zin[(size_t)row * 128 + j];
                v = (1.0f - beta_c) * zin + beta_c * v;
                Cout[(size_t)row * 128 + j] = v;
                s += v;
                ss = fmaf(v, v, ss);
            } else {
                Cout[(size_t)row * (NT * 16) + j] = v * (1.0f / dinv[row]) + bias[j];
            }
        }
        if (MODE == 1) {
            s  += __shfl_xor(s, 16);  s  += __shfl_xor(s, 32);
            ss += __shfl_xor(ss, 16); ss += __shfl_xor(ss, 32);
            if (kg == 0) {
                atomicAdd(&sstat[j], s);
                atomicAdd(&sstat[128 + j], ss);
            }
        }
    }
    if (MODE == 1) {
        __syncthreads();
        atomicAdd(&stats[tid], sstat[tid]);
    }
}

// ---------------------------------------------------------------------------
// Sparse aggregation, feature-sliced for XCD-L2 locality.
// hbp: bf16(dinv[u]*h[u]) slice-major (8 slices of 16 feats, each contiguous).
// slice = blockIdx % 8 -> pinned to one XCD (round-robin dispatch).
// Z[v,:] = 0.9*dinv[v]*(sum_edges hbp[s] + hbp[v]) + 0.1*h0[v,:]
// wave: 8 edge-groups (g) x 8 feature-pairs (lg); 8 rows per wave.
// ---------------------------------------------------------------------------
__global__ __launch_bounds__(256) void k_aggregate(const u16* __restrict__ hbp, const float* __restrict__ h0,
                                                   const int* __restrict__ rowptr, const int* __restrict__ ssrc,
                                                   const float* __restrict__ dinv,
                                                   float* __restrict__ Z, u16* __restrict__ Zb) {
    int slice = blockIdx.x & 7;
    int wave = threadIdx.x >> 6, lane = threadIdx.x & 63;
    int g = lane >> 3, lg = lane & 7;
    int vbase = (blockIdx.x >> 3) * 32 + wave * 8;
    const u16* hs = hbp + (size_t)slice * (N_NODES * 16);

    for (int r = 0; r < 8; ++r) {
        int v = vbase + r;
        if (v >= N_NODES) break;
        int beg = rowptr[v], end = rowptr[v + 1];
        float ax = 0.f, ay = 0.f;
        for (int p = beg + g; p < end; p += 8) {
            unsigned u = *(const unsigned*)(hs + (size_t)ssrc[p] * 16 + lg * 2);
            ax += bf2f((u16)(u & 0xffff));
            ay += bf2f((u16)(u >> 16));
        }
        if (g == 0) {  // self-loop
            unsigned u = *(const unsigned*)(hs + (size_t)v * 16 + lg * 2);
            ax += bf2f((u16)(u & 0xffff));
            ay += bf2f((u16)(u >> 16));
        }
        ax += __shfl_xor(ax, 8);  ay += __shfl_xor(ay, 8);
        ax += __shfl_xor(ax, 16); ay += __shfl_xor(ay, 16);
        ax += __shfl_xor(ax, 32); ay += __shfl_xor(ay, 32);
        if (g == 0) {
            float dv = dinv[v];
            float2 h0v = *(const float2*)(h0 + (size_t)v * 128 + slice * 16 + lg * 2);
            float zx = (1.0f - ALPHA_C) * dv * ax + ALPHA_C * h0v.x;
            float zy = (1.0f - ALPHA_C) * dv * ay + ALPHA_C * h0v.y;
            float2 zo; zo.x = zx; zo.y = zy;
            *(float2*)(Z + (size_t)v * 128 + slice * 16 + lg * 2) = zo;
            *(unsigned*)(Zb + ((size_t)slice * N_NODES + v) * 16 + lg * 2) =
                (unsigned)f2bf(zx) | ((unsigned)f2bf(zy) << 16);
        }
    }
}

// ---------------------------------------------------------------------------
// BN finalize (per-block, from layer stats slice) + apply + relu + prescale,
// write hbp slice-major bf16.
// ---------------------------------------------------------------------------
__global__ __launch_bounds__(256) void k_bn_relu(const float* __restrict__ Z, const float* __restrict__ stats,
                                                 const float* __restrict__ gamma, const float* __restrict__ betap,
                                                 const float* __restrict__ dinv, u16* __restrict__ hbp) {
    __shared__ float ssc[128], ssh[128];
    int t = threadIdx.x;
    if (t < 128) {
        float mean = stats[t] * (1.0f / N_NODES);
        float var = stats[128 + t] * (1.0f / N_NODES) - mean * mean;
        float istd = rsqrtf(var + BN_EPS);
        float sc = gamma[t] * istd;
        ssc[t] = sc;
        ssh[t] = betap[t] - mean * sc;
    }
    __syncthreads();
    for (size_t e = (size_t)blockIdx.x * 256 + t; e < (size_t)N_NODES * 32; e += (size_t)gridDim.x * 256) {
        size_t i = e * 4;
        int row = (int)(i >> 7), j = (int)(i & 127);
        float dv = dinv[row];
        float4 z = *(const float4*)(Z + i);
        float r0 = fmaxf(fmaf(z.x, ssc[j + 0], ssh[j + 0]), 0.f) * dv;
        float r1 = fmaxf(fmaf(z.y, ssc[j + 1], ssh[j + 1]), 0.f) * dv;
        float r2 = fmaxf(fmaf(z.z, ssc[j + 2], ssh[j + 2]), 0.f) * dv;
        float r3 = fmaxf(fmaf(z.w, ssc[j + 3], ssh[j + 3]), 0.f) * dv;
        uint2 o;
        o.x = (unsigned)f2bf(r0) | ((unsigned)f2bf(r1) << 16);
        o.y = (unsigned)f2bf(r2) | ((unsigned)f2bf(r3) << 16);
        *(uint2*)(hbp + ((size_t)(j >> 4) * N_NODES + row) * 16 + (j & 15)) = o;
    }
}

// ---------------------------------------------------------------------------

extern "C" void kernel_launch(void* const* d_in, const int* in_sizes, int n_in,
                              void* d_out, int out_size, void* d_ws, size_t ws_size,
                              hipStream_t stream) {
    const float* x      = (const float*)d_in[0];
    const int*   ei     = (const int*)d_in[1];
    const float* lin0_w = (const float*)d_in[2];
    const float* lin0_b = (const float*)d_in[3];
    const float* lin1_w = (const float*)d_in[4];
    const float* lin1_b = (const float*)d_in[5];
    const float* conv_w = (const float*)d_in[6];
    const float* bn_g   = (const float*)d_in[7];
    const float* bn_b   = (const float*)d_in[8];
    const int* e_src = ei;
    const int* e_dst = ei + N_EDGES;

    char* p = (char*)d_ws;
    auto alloc = [&](size_t bytes) -> void* {
        void* r = (void*)p;
        p += (bytes + 255) & ~(size_t)255;
        return r;
    };
    int*   cnt    = (int*)alloc((size_t)N_NODES * 4);
    int*   rowptr = (int*)alloc((size_t)(N_NODES + 1) * 4);
    int*   fill   = (int*)alloc((size_t)N_NODES * 4);
    float* dinv   = (float*)alloc((size_t)N_NODES * 4);
    int*   ssrc   = (int*)alloc((size_t)N_EDGES * 4);
    int*   bsum   = (int*)alloc(64 * 4);
    float* h0     = (float*)alloc((size_t)N_NODES * 128 * 4);
    float* Z      = (float*)alloc((size_t)N_NODES * 128 * 4);
    u16*   Zb     = (u16*)alloc((size_t)N_NODES * 128 * 2);   // slice-major; also xb
    u16*   hbp    = (u16*)alloc((size_t)N_NODES * 128 * 2);   // slice-major, dinv-prescaled
    u16*   wtb    = (u16*)alloc((size_t)(131072 + 16384 + 8192) * 2);
    float* stats  = (float*)alloc((size_t)NLAYERS * 256 * 4);

    const int nblk = (N_NODES + 255) / 256;
    const int eblk = (N_EDGES + 255) / 256;
    const int gblk = (N_NODES + 63) / 64;       // 782
    const int vblk = N_NODES * 128 / 4 / 256;   // 6250
    const int ablk = ((N_NODES + 31) / 32) * 8; // 12504

    // CSR + prep
    k_init<<<nblk, 256, 0, stream>>>(cnt, fill, stats);
    k_count<<<eblk, 256, 0, stream>>>(e_dst, cnt);
    k_dinv<<<nblk, 256, 0, stream>>>(cnt, dinv);
    k_scan_local<<<49, 1024, 0, stream>>>(cnt, rowptr, bsum);
    k_scan_top<<<1, 64, 0, stream>>>(bsum);
    k_scan_add<<<196, 256, 0, stream>>>(rowptr, bsum);
    k_scatter<<<eblk, 256, 0, stream>>>(e_src, e_dst, rowptr, fill, ssrc);
    k_convw<<<(131072 + 16384 + 8192 + 255) / 256, 256, 0, stream>>>(conv_w, lin0_w, lin1_w, wtb);
    k_convx<<<vblk, 256, 0, stream>>>(x, Zb);

    // input projection: h0(f32) + hbp(bf16, prescaled) = relu(x @ lin0_w.T + b)
    k_gemm_mfma<8, 0><<<gblk, 256, 0, stream>>>(Zb, wtb + 131072, lin0_b, nullptr, h0, hbp, nullptr, dinv, 0.f, N_NODES);

    for (int i = 0; i < NLAYERS; ++i) {
        k_aggregate<<<ablk, 256, 0, stream>>>(hbp, h0, rowptr, ssrc, dinv, Z, Zb);
        float beta = (float)log(0.5 / (double)(i + 1) + 1.0);
        k_gemm_mfma<8, 1><<<gblk, 256, 0, stream>>>(Zb, wtb + (size_t)i * 16384, nullptr, Z, Z, nullptr, stats + (size_t)i * 256, nullptr, beta, N_NODES);
        k_bn_relu<<<2048, 256, 0, stream>>>(Z, stats + (size_t)i * 256, bn_g + i * 128, bn_b + i * 128, dinv, hbp);
    }

    // output projection (A prescaled -> un-scale by 1/dinv in epilogue)
    k_gemm_mfma<4, 2><<<gblk, 256, 0, stream>>>(hbp, wtb + 147456, lin1_b, nullptr, (float*)d_out, nullptr, nullptr, dinv, 0.f, N_NODES);
}

// Round 4
// 870.663 us; speedup vs baseline: 1.7806x; 1.7806x over previous
//
#include <hip/hip_runtime.h>
#include <hip/hip_bf16.h>
#include <math.h>

#define N_NODES 50000
#define N_EDGES 800000
#define NLAYERS 8
#define ALPHA_C 0.1f
#define BN_EPS  1e-5f

typedef unsigned short u16;
typedef __attribute__((ext_vector_type(8))) short short8;
typedef __attribute__((ext_vector_type(4))) float f32x4;

static __device__ __forceinline__ u16 f2bf(float f) {
    unsigned u = __float_as_uint(f);
    unsigned r = (u + 0x7fffu + ((u >> 16) & 1u)) >> 16;
    return (u16)r;
}
static __device__ __forceinline__ float bf2f(u16 b) {
    return __uint_as_float((unsigned)b << 16);
}

// ---------------------------------------------------------------------------
// CSR build
// ---------------------------------------------------------------------------
__global__ __launch_bounds__(256) void k_init(int* cnt, int* fill, float* stats) {
    int i = blockIdx.x * 256 + threadIdx.x;
    if (i < N_NODES) { cnt[i] = 0; fill[i] = 0; }
    if (i < NLAYERS * 256) stats[i] = 0.0f;
}

__global__ __launch_bounds__(256) void k_count(const int* __restrict__ dst, int* cnt) {
    int e = blockIdx.x * 256 + threadIdx.x;
    if (e < N_EDGES) atomicAdd(&cnt[dst[e]], 1);
}

__global__ __launch_bounds__(256) void k_dinv(const int* __restrict__ cnt, float* __restrict__ dinv) {
    int i = blockIdx.x * 256 + threadIdx.x;
    if (i < N_NODES) dinv[i] = rsqrtf((float)(cnt[i] + 1));  // +1 self-loop
}

__global__ __launch_bounds__(1024) void k_scan_local(const int* __restrict__ cnt,
                                                     int* __restrict__ rowptr, int* __restrict__ bsum) {
    __shared__ int tmp[1024];
    int t = threadIdx.x;
    int i = blockIdx.x * 1024 + t;
    int v = (i < N_NODES) ? cnt[i] : 0;
    tmp[t] = v;
    __syncthreads();
    for (int off = 1; off < 1024; off <<= 1) {
        int y = (t >= off) ? tmp[t - off] : 0;
        __syncthreads();
        tmp[t] += y;
        __syncthreads();
    }
    if (i < N_NODES) rowptr[i] = tmp[t] - v;
    if (t == 1023) bsum[blockIdx.x] = tmp[t];
}

__global__ void k_scan_top(int* bsum) {
    __shared__ int tmp[64];
    int t = threadIdx.x;
    int v = (t < 49) ? bsum[t] : 0;
    tmp[t] = v;
    __syncthreads();
    for (int off = 1; off < 64; off <<= 1) {
        int y = (t >= off) ? tmp[t - off] : 0;
        __syncthreads();
        tmp[t] += y;
        __syncthreads();
    }
    if (t < 49) bsum[t] = tmp[t] - v;
}

__global__ __launch_bounds__(256) void k_scan_add(int* __restrict__ rowptr, const int* __restrict__ bsum) {
    int i = blockIdx.x * 256 + threadIdx.x;
    if (i < N_NODES) rowptr[i] += bsum[i >> 10];
    if (i == 0) rowptr[N_NODES] = N_EDGES;
}

__global__ __launch_bounds__(256) void k_scatter(const int* __restrict__ src, const int* __restrict__ dst,
                                                 const int* __restrict__ rowptr, int* fill,
                                                 u16* __restrict__ ssrc) {
    int e = blockIdx.x * 256 + threadIdx.x;
    if (e < N_EDGES) {
        int d = dst[e];
        int pos = rowptr[d] + atomicAdd(&fill[d], 1);
        ssrc[pos] = (u16)src[e];
    }
}

// ---------------------------------------------------------------------------
// Weight convert: fp32 -> bf16, [j][k], XOR-swizzled (k' = k ^ ((j&7)<<3))
// wtb layout (elements): conv layer i at i*16384, lin0 at 131072, lin1 at 147456
// ---------------------------------------------------------------------------
__global__ __launch_bounds__(256) void k_convw(const float* __restrict__ conv_w,
                                               const float* __restrict__ lin0_w,
                                               const float* __restrict__ lin1_w,
                                               u16* __restrict__ wtb) {
    int t = blockIdx.x * 256 + threadIdx.x;
    if (t < 131072) {                       // conv: B[j][k] = conv_w[i][k][j]
        int j = (t >> 7) & 127, k = t & 127;
        int i = t >> 14;
        float v = conv_w[(i << 14) + (k << 7) + j];
        wtb[(t & ~127) | (k ^ ((j & 7) << 3))] = f2bf(v);
    } else if (t < 131072 + 16384) {        // lin0_w [128][128] already [j][k]
        int u = t - 131072;
        int j = u >> 7, k = u & 127;
        wtb[131072 + ((u & ~127) | (k ^ ((j & 7) << 3)))] = f2bf(lin0_w[u]);
    } else if (t < 131072 + 16384 + 8192) { // lin1_w [64][128]
        int u = t - 147456;
        int j = u >> 7, k = u & 127;
        wtb[147456 + ((u & ~127) | (k ^ ((j & 7) << 3)))] = f2bf(lin1_w[u]);
    }
}

// x (fp32 row-major) -> bf16 slice-major: xb[((j>>4)*N + row)*16 + (j&15)]
__global__ __launch_bounds__(256) void k_convx(const float* __restrict__ x, u16* __restrict__ xb) {
    size_t i = ((size_t)blockIdx.x * 256 + threadIdx.x) * 4;
    int row = (int)(i >> 7), j = (int)(i & 127);
    float4 v = *(const float4*)(x + i);
    uint2 o;
    o.x = (unsigned)f2bf(v.x) | ((unsigned)f2bf(v.y) << 16);
    o.y = (unsigned)f2bf(v.z) | ((unsigned)f2bf(v.w) << 16);
    *(uint2*)(xb + ((size_t)(j >> 4) * N_NODES + row) * 16 + (j & 15)) = o;
}

// ---------------------------------------------------------------------------
// MFMA GEMM: 64 rows/block, 4 waves, K=128. A bf16 slice-major, W [j][k] swz.
// MODE 0: v=relu(acc+bias); h0b=bf16(v); hbp=bf16(v*dinv)        (both slice-major)
// MODE 1: v=(1-beta)*bf2f(A) + beta*acc; Zf=v (f32 slice-major); BN stats atomics
// MODE 2: outF[row*64+j] = acc/dinv[row] + bias[j]               (row-major)
// ---------------------------------------------------------------------------
template<int NT, int MODE>
__global__ __launch_bounds__(256) void k_gemm_mfma(const u16* __restrict__ A,
                                                   const u16* __restrict__ Wg,
                                                   const float* __restrict__ bias,
                                                   float* __restrict__ Zf,
                                                   u16* __restrict__ h0b,
                                                   u16* __restrict__ hbp,
                                                   float* __restrict__ outF,
                                                   float* __restrict__ stats,
                                                   const float* __restrict__ dinv,
                                                   float beta_c, int M) {
    __shared__ u16 Ws[NT * 16 * 128];
    __shared__ float sstat[256];
    int tid = threadIdx.x;

    {
        const float4* srcv = (const float4*)Wg;
        float4* dstv = (float4*)Ws;
#pragma unroll
        for (int i = 0; i < NT; ++i) dstv[tid + i * 256] = srcv[tid + i * 256];
    }
    if (MODE == 1) sstat[tid] = 0.f;

    int wave = tid >> 6, lane = tid & 63;
    int r0 = blockIdx.x * 64 + wave * 16;
    int kg = lane >> 4;            // k-group 0..3
    int cl = lane & 15;

    int arow = r0 + cl;
    int acl = arow < M ? arow : M - 1;
    short8 afrag[4];
#pragma unroll
    for (int kk = 0; kk < 4; ++kk) {
        int s = kk * 2 + (kg >> 1);  // slice of k-range kk*32+kg*8..+7
        afrag[kk] = *(const short8*)(A + ((size_t)s * N_NODES + acl) * 16 + (kg & 1) * 8);
    }

    __syncthreads();

    f32x4 acc[NT];
#pragma unroll
    for (int nt = 0; nt < NT; ++nt) {
        acc[nt] = (f32x4){0.f, 0.f, 0.f, 0.f};
        int j = nt * 16 + cl;
        const u16* wrow = Ws + j * 128;
        int sw = (j & 7) << 3;
#pragma unroll
        for (int kk = 0; kk < 4; ++kk) {
            short8 b = *(const short8*)(wrow + ((kk * 32 + kg * 8) ^ sw));
            acc[nt] = __builtin_amdgcn_mfma_f32_16x16x32_bf16(afrag[kk], b, acc[nt], 0, 0, 0);
        }
    }

    int rbase = r0 + kg * 4;
    float dvr[4];
    if (MODE != 1) {
#pragma unroll
        for (int reg = 0; reg < 4; ++reg) {
            int row = rbase + reg;
            dvr[reg] = (row < M) ? dinv[row] : 1.f;
        }
    }

#pragma unroll
    for (int nt = 0; nt < NT; ++nt) {
        int j = nt * 16 + cl;
        float s = 0.f, ss = 0.f;
#pragma unroll
        for (int reg = 0; reg < 4; ++reg) {
            int row = rbase + reg;
            if (row >= M) continue;
            float v = acc[nt][reg];
            size_t idx = ((size_t)nt * N_NODES + row) * 16 + cl;
            if (MODE == 0) {
                v = fmaxf(v + bias[j], 0.f);
                h0b[idx] = f2bf(v);
                hbp[idx] = f2bf(v * dvr[reg]);
            } else if (MODE == 1) {
                float zin = bf2f(A[idx]);
                v = (1.0f - beta_c) * zin + beta_c * v;
                Zf[idx] = v;
                s += v;
                ss = fmaf(v, v, ss);
            } else {
                outF[(size_t)row * (NT * 16) + j] = v / dvr[reg] + bias[j];
            }
        }
        if (MODE == 1) {
            s  += __shfl_xor(s, 16);  s  += __shfl_xor(s, 32);
            ss += __shfl_xor(ss, 16); ss += __shfl_xor(ss, 32);
            if (kg == 0) {
                atomicAdd(&sstat[j], s);
                atomicAdd(&sstat[128 + j], ss);
            }
        }
    }
    if (MODE == 1) {
        __syncthreads();
        atomicAdd(&stats[tid], sstat[tid]);
    }
}

// ---------------------------------------------------------------------------
// Sparse aggregation v3: slice = blockIdx&7 (XCD-pinned), 8 rows/wave,
// 8 lanes/row (lane lg owns feat pair 2lg), serial edges, 4-way unrolled.
// Zb[v] = bf16( 0.9*dinv[v]*(sum hbp[src] + hbp[v]) + 0.1*h0b[v] )
// ---------------------------------------------------------------------------
__global__ __launch_bounds__(256) void k_aggregate(const u16* __restrict__ hbp, const u16* __restrict__ h0b,
                                                   const int* __restrict__ rowptr, const u16* __restrict__ ssrc,
                                                   const float* __restrict__ dinv,
                                                   u16* __restrict__ Zb) {
    int slice = blockIdx.x & 7;
    int wave = threadIdx.x >> 6, lane = threadIdx.x & 63;
    int rg = lane >> 3, lg = lane & 7;
    int v = (blockIdx.x >> 3) * 32 + wave * 8 + rg;
    if (v >= N_NODES) return;
    const u16* hs = hbp + (size_t)slice * (N_NODES * 16);
    int beg = rowptr[v], end = rowptr[v + 1];

    float ax, ay;
    {   // self-loop
        unsigned u = *(const unsigned*)(hs + (size_t)v * 16 + lg * 2);
        ax = __uint_as_float(u << 16);
        ay = __uint_as_float(u & 0xffff0000u);
    }
    int p = beg;
    for (; p + 4 <= end; p += 4) {
        int s0 = ssrc[p], s1 = ssrc[p + 1], s2 = ssrc[p + 2], s3 = ssrc[p + 3];
        unsigned u0 = *(const unsigned*)(hs + (size_t)s0 * 16 + lg * 2);
        unsigned u1 = *(const unsigned*)(hs + (size_t)s1 * 16 + lg * 2);
        unsigned u2 = *(const unsigned*)(hs + (size_t)s2 * 16 + lg * 2);
        unsigned u3 = *(const unsigned*)(hs + (size_t)s3 * 16 + lg * 2);
        ax += __uint_as_float(u0 << 16); ay += __uint_as_float(u0 & 0xffff0000u);
        ax += __uint_as_float(u1 << 16); ay += __uint_as_float(u1 & 0xffff0000u);
        ax += __uint_as_float(u2 << 16); ay += __uint_as_float(u2 & 0xffff0000u);
        ax += __uint_as_float(u3 << 16); ay += __uint_as_float(u3 & 0xffff0000u);
    }
    for (; p < end; ++p) {
        int s = ssrc[p];
        unsigned u = *(const unsigned*)(hs + (size_t)s * 16 + lg * 2);
        ax += __uint_as_float(u << 16); ay += __uint_as_float(u & 0xffff0000u);
    }

    float dv = dinv[v];
    unsigned uh = *(const unsigned*)(h0b + ((size_t)slice * N_NODES + v) * 16 + lg * 2);
    float zx = (1.0f - ALPHA_C) * dv * ax + ALPHA_C * __uint_as_float(uh << 16);
    float zy = (1.0f - ALPHA_C) * dv * ay + ALPHA_C * __uint_as_float(uh & 0xffff0000u);
    *(unsigned*)(Zb + ((size_t)slice * N_NODES + v) * 16 + lg * 2) =
        (unsigned)f2bf(zx) | ((unsigned)f2bf(zy) << 16);
}

// ---------------------------------------------------------------------------
// BN finalize (from layer stats) + apply + relu + dinv-prescale.
// Zf f32 slice-major (linear) -> hbp bf16 slice-major (linear).
// ---------------------------------------------------------------------------
__global__ __launch_bounds__(256) void k_bn_relu(const float* __restrict__ Zf, const float* __restrict__ stats,
                                                 const float* __restrict__ gamma, const float* __restrict__ betap,
                                                 const float* __restrict__ dinv, u16* __restrict__ hbp) {
    __shared__ float ssc[128], ssh[128];
    int t = threadIdx.x;
    if (t < 128) {
        float mean = stats[t] * (1.0f / N_NODES);
        float var = stats[128 + t] * (1.0f / N_NODES) - mean * mean;
        float istd = rsqrtf(var + BN_EPS);
        float sc = gamma[t] * istd;
        ssc[t] = sc;
        ssh[t] = betap[t] - mean * sc;
    }
    __syncthreads();
    int e4 = blockIdx.x * 256 + t;          // 1.6M lanes, 4 elems each
    if (e4 >= N_NODES * 32) return;
    int slice = e4 / (N_NODES * 4);
    int rem = e4 - slice * (N_NODES * 4);
    int row = rem >> 2;
    int j0 = slice * 16 + (rem & 3) * 4;
    float dv = dinv[row];
    float4 z = *(const float4*)(Zf + (size_t)e4 * 4);
    float r0 = fmaxf(fmaf(z.x, ssc[j0 + 0], ssh[j0 + 0]), 0.f) * dv;
    float r1 = fmaxf(fmaf(z.y, ssc[j0 + 1], ssh[j0 + 1]), 0.f) * dv;
    float r2 = fmaxf(fmaf(z.z, ssc[j0 + 2], ssh[j0 + 2]), 0.f) * dv;
    float r3 = fmaxf(fmaf(z.w, ssc[j0 + 3], ssh[j0 + 3]), 0.f) * dv;
    uint2 o;
    o.x = (unsigned)f2bf(r0) | ((unsigned)f2bf(r1) << 16);
    o.y = (unsigned)f2bf(r2) | ((unsigned)f2bf(r3) << 16);
    *(uint2*)(hbp + (size_t)e4 * 4) = o;
}

// ---------------------------------------------------------------------------

extern "C" void kernel_launch(void* const* d_in, const int* in_sizes, int n_in,
                              void* d_out, int out_size, void* d_ws, size_t ws_size,
                              hipStream_t stream) {
    const float* x      = (const float*)d_in[0];
    const int*   ei     = (const int*)d_in[1];
    const float* lin0_w = (const float*)d_in[2];
    const float* lin0_b = (const float*)d_in[3];
    const float* lin1_w = (const float*)d_in[4];
    const float* lin1_b = (const float*)d_in[5];
    const float* conv_w = (const float*)d_in[6];
    const float* bn_g   = (const float*)d_in[7];
    const float* bn_b   = (const float*)d_in[8];
    const int* e_src = ei;
    const int* e_dst = ei + N_EDGES;

    char* p = (char*)d_ws;
    auto alloc = [&](size_t bytes) -> void* {
        void* r = (void*)p;
        p += (bytes + 255) & ~(size_t)255;
        return r;
    };
    int*   cnt    = (int*)alloc((size_t)N_NODES * 4);
    int*   rowptr = (int*)alloc((size_t)(N_NODES + 1) * 4);
    int*   fill   = (int*)alloc((size_t)N_NODES * 4);
    float* dinv   = (float*)alloc((size_t)N_NODES * 4);
    u16*   ssrc   = (u16*)alloc((size_t)N_EDGES * 2);
    int*   bsum   = (int*)alloc(64 * 4);
    u16*   h0b    = (u16*)alloc((size_t)N_NODES * 128 * 2);   // slice-major
    float* Zf     = (float*)alloc((size_t)N_NODES * 128 * 4); // slice-major f32
    u16*   Zb     = (u16*)alloc((size_t)N_NODES * 128 * 2);   // slice-major; also xb
    u16*   hbp    = (u16*)alloc((size_t)N_NODES * 128 * 2);   // slice-major, dinv-prescaled
    u16*   wtb    = (u16*)alloc((size_t)(131072 + 16384 + 8192) * 2);
    float* stats  = (float*)alloc((size_t)NLAYERS * 256 * 4);

    const int nblk = (N_NODES + 255) / 256;
    const int eblk = (N_EDGES + 255) / 256;
    const int gblk = (N_NODES + 63) / 64;        // 782
    const int vblk = N_NODES * 128 / 4 / 256;    // 6250
    const int ablk = ((N_NODES + 31) / 32) * 8;  // 12504
    const int bnblk = (N_NODES * 32 + 255) / 256;// 6250

    // CSR + prep
    k_init<<<nblk, 256, 0, stream>>>(cnt, fill, stats);
    k_count<<<eblk, 256, 0, stream>>>(e_dst, cnt);
    k_dinv<<<nblk, 256, 0, stream>>>(cnt, dinv);
    k_scan_local<<<49, 1024, 0, stream>>>(cnt, rowptr, bsum);
    k_scan_top<<<1, 64, 0, stream>>>(bsum);
    k_scan_add<<<196, 256, 0, stream>>>(rowptr, bsum);
    k_scatter<<<eblk, 256, 0, stream>>>(e_src, e_dst, rowptr, fill, ssrc);
    k_convw<<<(131072 + 16384 + 8192 + 255) / 256, 256, 0, stream>>>(conv_w, lin0_w, lin1_w, wtb);
    k_convx<<<vblk, 256, 0, stream>>>(x, Zb);

    // input projection: h0b + hbp = relu(x @ lin0_w.T + b)
    k_gemm_mfma<8, 0><<<gblk, 256, 0, stream>>>(Zb, wtb + 131072, lin0_b, nullptr, h0b, hbp, nullptr, nullptr, dinv, 0.f, N_NODES);

    for (int i = 0; i < NLAYERS; ++i) {
        k_aggregate<<<ablk, 256, 0, stream>>>(hbp, h0b, rowptr, ssrc, dinv, Zb);
        float beta = (float)log(0.5 / (double)(i + 1) + 1.0);
        k_gemm_mfma<8, 1><<<gblk, 256, 0, stream>>>(Zb, wtb + (size_t)i * 16384, nullptr, Zf, nullptr, nullptr, nullptr, stats + (size_t)i * 256, nullptr, beta, N_NODES);
        k_bn_relu<<<bnblk, 256, 0, stream>>>(Zf, stats + (size_t)i * 256, bn_g + i * 128, bn_b + i * 128, dinv, hbp);
    }

    // output projection
    k_gemm_mfma<4, 2><<<gblk, 256, 0, stream>>>(hbp, wtb + 147456, lin1_b, nullptr, nullptr, nullptr, (float*)d_out, nullptr, dinv, 0.f, N_NODES);
}